// Round 2
// baseline (645.358 us; speedup 1.0000x reference)
//
#include <hip/hip_runtime.h>
#include <math.h>

#define BB 2
#define SS 2048
#define NN 2049
#define MM (BB*NN)      // 4098 rows
#define DD 256
#define HR 128          // HEADS*RANK
#define NHEAD 4
#define WINW 64
#define KW 129          // 2*WIN+1
#define DFF 512
#define EPSF 1e-6f
#define TT 8            // attn token tile
#define TPB 257         // attn tiles per batch = ceil(NN/8)
#define PT 16           // gemm token tile

// ---------- reduction helpers (wave=64) ----------
__device__ __forceinline__ float wave_sum(float v) {
    v += __shfl_down(v, 32, 64);
    v += __shfl_down(v, 16, 64);
    v += __shfl_down(v, 8, 64);
    v += __shfl_down(v, 4, 64);
    v += __shfl_down(v, 2, 64);
    v += __shfl_down(v, 1, 64);
    return v;
}
__device__ __forceinline__ float wave_max(float v) {
    v = fmaxf(v, __shfl_down(v, 32, 64));
    v = fmaxf(v, __shfl_down(v, 16, 64));
    v = fmaxf(v, __shfl_down(v, 8, 64));
    v = fmaxf(v, __shfl_down(v, 4, 64));
    v = fmaxf(v, __shfl_down(v, 2, 64));
    v = fmaxf(v, __shfl_down(v, 1, 64));
    return v;
}
__device__ __forceinline__ float block_sum(float v, float* red) {
    v = wave_sum(v);
    __syncthreads();
    if ((threadIdx.x & 63) == 0) red[threadIdx.x >> 6] = v;
    __syncthreads();
    return red[0] + red[1] + red[2] + red[3];
}
__device__ __forceinline__ float sgnf(float x) {
    return (x > 0.f) ? 1.f : ((x < 0.f) ? -1.f : 0.f);
}

// ---------- embed ----------
__global__ void embed_kernel(const int* __restrict__ ids,
                             const float* __restrict__ emb,
                             const float* __restrict__ pos,
                             const float* __restrict__ anchor_val,
                             const float* __restrict__ anchor_state,
                             const float* __restrict__ Ws,
                             const float* __restrict__ bs,
                             float* __restrict__ val,
                             float* __restrict__ state) {
    __shared__ float red[4];
    int row = blockIdx.x;
    int t = threadIdx.x;
    int b = row / NN, n = row % NN;
    float e;
    if (n == 0) {
        e = anchor_val[t];
    } else {
        int id = ids[b * SS + (n - 1)];
        e = emb[(size_t)id * DD + t] + pos[(size_t)(n - 1) * DD + t];
    }
    float ss = block_sum(e * e, red);
    float ts = block_sum(e * Ws[t], red);
    float rn = 1.f / fmaxf(sqrtf(ss), EPSF);
    val[(size_t)row * DD + t] = e * rn;
    if (t == 0) state[row] = (n == 0) ? anchor_state[0] : (ts + bs[0]);
}

// ---------- q/k projection, 16-token tile ----------
__global__ void proj_kernel(const float* __restrict__ val,
                            const float* __restrict__ U,
                            const float* __restrict__ V,
                            float* __restrict__ q,
                            float* __restrict__ k) {
    __shared__ float vT[DD][20];   // stride 20 floats = 80B (16B-aligned rows)
    int m0 = blockIdx.x * PT;
    int t = threadIdx.x;
    #pragma unroll
    for (int m = 0; m < PT; m++) {
        int row = m0 + m;
        vT[t][m] = (row < MM) ? val[(size_t)row * DD + t] : 0.f;
    }
    __syncthreads();
    const float* Wm = (t < HR) ? U : V;
    int o = t & 127;
    float acc[PT];
    #pragma unroll
    for (int m = 0; m < PT; m++) acc[m] = 0.f;
    for (int d = 0; d < DD; d++) {
        float w = Wm[(size_t)d * HR + o];
        float4 vv[4];
        vv[0] = *(const float4*)&vT[d][0];
        vv[1] = *(const float4*)&vT[d][4];
        vv[2] = *(const float4*)&vT[d][8];
        vv[3] = *(const float4*)&vT[d][12];
        #pragma unroll
        for (int g = 0; g < 4; g++) {
            acc[g*4+0] += vv[g].x * w;
            acc[g*4+1] += vv[g].y * w;
            acc[g*4+2] += vv[g].z * w;
            acc[g*4+3] += vv[g].w * w;
        }
    }
    float* outp = (t < HR) ? q : k;
    #pragma unroll
    for (int m = 0; m < PT; m++) {
        int row = m0 + m;
        if (row < MM) outp[(size_t)row * HR + o] = acc[m];
    }
}

// ---------- windowed signed-softmax attention, 8-token tile ----------
__global__ void attn_kernel(const float* __restrict__ val_in,
                            const float* __restrict__ state_in,
                            const float* __restrict__ q,
                            const float* __restrict__ k,
                            float* __restrict__ val_out,
                            float* __restrict__ dstate_out) {
    __shared__ float qs[TT][HR];        // 4KB
    __shared__ float sc[TT][KW + 3];    // 4.1KB
    __shared__ float wgt2[144][TT];     // 4.5KB, jj-major, zero-padded
    __shared__ float redS[TT][4];
    __shared__ float redM[TT][4];
    int b = blockIdx.x / TPB;
    int n0 = (blockIdx.x % TPB) * TT;
    int nt = NN - n0; if (nt > TT) nt = TT;
    int t = threadIdx.x;

    for (int i = t; i < nt * HR; i += 256)
        qs[i >> 7][i & 127] = q[((size_t)(b * NN + n0)) * HR + i];
    for (int i = t; i < 144 * TT; i += 256) ((float*)wgt2)[i] = 0.f;
    __syncthreads();

    // scores: nt tokens x 129 taps
    for (int idx = t; idx < nt * KW; idx += 256) {
        int m = idx / KW;
        int tap = idx - m * KW;
        int j = n0 + m - WINW + tap;
        float sv = 0.f;
        if (j >= 0 && j < NN) {
            const float4* kr = (const float4*)&k[((size_t)(b * NN + j)) * HR];
            const float4* qr = (const float4*)&qs[m][0];
            float smax = -INFINITY;
            #pragma unroll
            for (int h = 0; h < NHEAD; h++) {
                float acc = 0.f;
                #pragma unroll
                for (int i4 = 0; i4 < 8; i4++) {
                    float4 kv = kr[h * 8 + i4];
                    float4 qv = qr[h * 8 + i4];
                    acc += kv.x*qv.x + kv.y*qv.y + kv.z*qv.z + kv.w*qv.w;
                }
                smax = fmaxf(smax, acc);
            }
            sv = smax * 0.17677669529663687f;   // 1/sqrt(RANK)
        }
        sc[m][tap] = sv;
    }
    __syncthreads();

    // softmax per token: 32-lane group per token
    {
        int g = t >> 5, l = t & 31;
        if (g < nt) {
            int n = n0 + g;
            int lo = (n - WINW < 0) ? (WINW - n) : 0;
            int hi = (n + WINW > NN - 1) ? (KW - 1 - (n + WINW - (NN - 1))) : (KW - 1);
            float mx = -INFINITY;
            for (int tap = lo + l; tap <= hi; tap += 32)
                mx = fmaxf(mx, fabsf(sc[g][tap]));
            for (int off = 16; off > 0; off >>= 1)
                mx = fmaxf(mx, __shfl_xor(mx, off, 64));
            float sum = 0.f;
            for (int tap = lo + l; tap <= hi; tap += 32)
                sum += expf(fabsf(sc[g][tap]) - mx);
            for (int off = 16; off > 0; off >>= 1)
                sum += __shfl_xor(sum, off, 64);
            float inv = 1.f / sum;
            float ds = 0.f;
            for (int tap = lo + l; tap <= hi; tap += 32) {
                float s = sc[g][tap];
                float w = sgnf(s) * expf(fabsf(s) - mx) * inv;
                wgt2[tap + g][g] = w;
                ds += w * state_in[b * NN + (n - WINW + tap)];
            }
            for (int off = 16; off > 0; off >>= 1)
                ds += __shfl_xor(ds, off, 64);
            if (l == 0) dstate_out[b * NN + n] = ds;
        }
    }
    __syncthreads();

    // dval: each thread owns d=t; loop over window rows once, 8 tokens per row
    int base = n0 - WINW;
    int jlo = (base < 0) ? -base : 0;
    int jmax = nt - 1 + 2 * WINW;
    int jhi = (base + jmax > NN - 1) ? (NN - 1 - base) : jmax;
    const float* vb = val_in + ((size_t)(b * NN + base)) * DD + t;
    float acc[TT] = {0.f,0.f,0.f,0.f,0.f,0.f,0.f,0.f};
    #pragma unroll 2
    for (int jj = jlo; jj <= jhi; jj++) {
        float v = vb[(size_t)jj * DD];
        float4 w0 = *(const float4*)&wgt2[jj][0];
        float4 w1 = *(const float4*)&wgt2[jj][4];
        acc[0] += v * w0.x; acc[1] += v * w0.y; acc[2] += v * w0.z; acc[3] += v * w0.w;
        acc[4] += v * w1.x; acc[5] += v * w1.y; acc[6] += v * w1.z; acc[7] += v * w1.w;
    }

    // epilogue: residual + conditional unit-norm, per token
    int wid = t >> 6;
    float upd[TT];
    #pragma unroll
    for (int m = 0; m < TT; m++) {
        float vold = 0.f;
        if (m < nt) vold = val_in[((size_t)(b * NN + n0 + m)) * DD + t];
        float u = vold + acc[m];
        upd[m] = u;
        float s = wave_sum(u * u);
        float mx = wave_max(fabsf(acc[m]));
        if ((t & 63) == 0) { redS[m][wid] = s; redM[m][wid] = mx; }
    }
    __syncthreads();
    for (int m = 0; m < nt; m++) {
        float ss = redS[m][0] + redS[m][1] + redS[m][2] + redS[m][3];
        float mab = fmaxf(fmaxf(redM[m][0], redM[m][1]), fmaxf(redM[m][2], redM[m][3]));
        float rn = 1.f / fmaxf(sqrtf(ss), EPSF);
        float u = upd[m];
        val_out[((size_t)(b * NN + n0 + m)) * DD + t] = (mab > 0.f) ? u * rn : u;
    }
}

// ---------- state update: signed softmax over N per batch row ----------
__global__ void state_kernel(const float* __restrict__ state_in,
                             const float* __restrict__ dstate,
                             float* __restrict__ state_out) {
    __shared__ float xs[NN];
    __shared__ float redA[16];
    __shared__ float redB[16];
    int b = blockIdx.x, t = threadIdx.x;
    float lmax = -INFINITY;
    for (int n = t; n < NN; n += 1024) {
        float x = state_in[b * NN + n] + dstate[b * NN + n];
        xs[n] = x;
        lmax = fmaxf(lmax, fabsf(x));
    }
    lmax = wave_max(lmax);
    if ((t & 63) == 0) redA[t >> 6] = lmax;
    __syncthreads();
    float m = redA[0];
    #pragma unroll
    for (int i = 1; i < 16; i++) m = fmaxf(m, redA[i]);
    float lsum = 0.f;
    for (int n = t; n < NN; n += 1024) lsum += expf(fabsf(xs[n]) - m);
    lsum = wave_sum(lsum);
    if ((t & 63) == 0) redB[t >> 6] = lsum;
    __syncthreads();
    float ssum = 0.f;
    #pragma unroll
    for (int i = 0; i < 16; i++) ssum += redB[i];
    float inv = 1.f / ssum;
    for (int n = t; n < NN; n += 1024) {
        float x = xs[n];
        state_out[b * NN + n] = sgnf(x) * expf(fabsf(x) - m) * inv;
    }
}

// ---------- FFN fused, 16-token tile ----------
__global__ void ffn_kernel(const float* __restrict__ val_in,
                           const float* __restrict__ W1,   // (D, 2D)
                           const float* __restrict__ b1,
                           const float* __restrict__ W2,   // (2D, D)
                           const float* __restrict__ b2,
                           float* __restrict__ val_out) {
    __shared__ float vT[DD][20];    // 20KB
    __shared__ float hT[DFF][20];   // 40KB
    __shared__ float redS[PT][4];
    int m0 = blockIdx.x * PT;
    int t = threadIdx.x;
    #pragma unroll
    for (int m = 0; m < PT; m++) {
        int row = m0 + m;
        vT[t][m] = (row < MM) ? val_in[(size_t)row * DD + t] : 0.f;
    }
    __syncthreads();
    // GEMM1 + gelu: outputs t and t+256
    float acc0[PT], acc1[PT];
    #pragma unroll
    for (int m = 0; m < PT; m++) { acc0[m] = 0.f; acc1[m] = 0.f; }
    for (int d = 0; d < DD; d++) {
        float w0 = W1[(size_t)d * DFF + t];
        float w1 = W1[(size_t)d * DFF + t + 256];
        float4 vv[4];
        vv[0] = *(const float4*)&vT[d][0];
        vv[1] = *(const float4*)&vT[d][4];
        vv[2] = *(const float4*)&vT[d][8];
        vv[3] = *(const float4*)&vT[d][12];
        #pragma unroll
        for (int g = 0; g < 4; g++) {
            acc0[g*4+0] += vv[g].x * w0;  acc1[g*4+0] += vv[g].x * w1;
            acc0[g*4+1] += vv[g].y * w0;  acc1[g*4+1] += vv[g].y * w1;
            acc0[g*4+2] += vv[g].z * w0;  acc1[g*4+2] += vv[g].z * w1;
            acc0[g*4+3] += vv[g].w * w0;  acc1[g*4+3] += vv[g].w * w1;
        }
    }
    float bb0 = b1[t], bb1 = b1[t + 256];
    #pragma unroll
    for (int m = 0; m < PT; m++) {
        float x0 = acc0[m] + bb0;
        float x1 = acc1[m] + bb1;
        hT[t][m]       = 0.5f * x0 * (1.f + erff(x0 * 0.70710678118654752f));
        hT[t + 256][m] = 0.5f * x1 * (1.f + erff(x1 * 0.70710678118654752f));
    }
    __syncthreads();
    // GEMM2
    float acc2[PT];
    #pragma unroll
    for (int m = 0; m < PT; m++) acc2[m] = 0.f;
    for (int j = 0; j < DFF; j++) {
        float w = W2[(size_t)j * DD + t];
        float4 hh[4];
        hh[0] = *(const float4*)&hT[j][0];
        hh[1] = *(const float4*)&hT[j][4];
        hh[2] = *(const float4*)&hT[j][8];
        hh[3] = *(const float4*)&hT[j][12];
        #pragma unroll
        for (int g = 0; g < 4; g++) {
            acc2[g*4+0] += hh[g].x * w;
            acc2[g*4+1] += hh[g].y * w;
            acc2[g*4+2] += hh[g].z * w;
            acc2[g*4+3] += hh[g].w * w;
        }
    }
    // epilogue: residual + bias + unit-norm (wave partials, one barrier)
    float bb = b2[t];
    int wid = t >> 6;
    float y[PT];
    #pragma unroll
    for (int m = 0; m < PT; m++) {
        y[m] = vT[t][m] + acc2[m] + bb;
        float s = wave_sum(y[m] * y[m]);
        if ((t & 63) == 0) redS[m][wid] = s;
    }
    __syncthreads();
    #pragma unroll
    for (int m = 0; m < PT; m++) {
        int row = m0 + m;
        if (row < MM) {
            float ss = redS[m][0] + redS[m][1] + redS[m][2] + redS[m][3];
            float rn = 1.f / fmaxf(sqrtf(ss), EPSF);
            val_out[(size_t)row * DD + t] = y[m] * rn;
        }
    }
}

extern "C" void kernel_launch(void* const* d_in, const int* in_sizes, int n_in,
                              void* d_out, int out_size, void* d_ws, size_t ws_size,
                              hipStream_t stream) {
    const int*   ids          = (const int*)d_in[0];
    const float* emb          = (const float*)d_in[1];
    const float* pos          = (const float*)d_in[2];
    const float* anchor_val   = (const float*)d_in[3];
    const float* anchor_state = (const float*)d_in[4];
    const float* Ws           = (const float*)d_in[5];
    const float* bs           = (const float*)d_in[6];
    const float* U            = (const float*)d_in[7];
    const float* V            = (const float*)d_in[8];
    const float* W1           = (const float*)d_in[9];
    const float* b1           = (const float*)d_in[10];
    const float* W2           = (const float*)d_in[11];
    const float* b2           = (const float*)d_in[12];
    float* out = (float*)d_out;

    float* w    = (float*)d_ws;
    float* valA = w;
    float* valB = valA + (size_t)MM * DD;
    float* qbuf = valB + (size_t)MM * DD;
    float* kbuf = qbuf + (size_t)MM * HR;
    float* st0  = kbuf + (size_t)MM * HR;
    float* st1  = st0 + MM;
    float* dst  = st1 + MM;

    embed_kernel<<<MM, 256, 0, stream>>>(ids, emb, pos, anchor_val, anchor_state,
                                         Ws, bs, valA, st0);
    float* s_in = st0;
    float* s_out = st1;
    for (int l = 0; l < 3; l++) {
        proj_kernel<<<(MM + PT - 1) / PT, 256, 0, stream>>>(
            valA, U + (size_t)l * DD * HR, V + (size_t)l * DD * HR, qbuf, kbuf);
        attn_kernel<<<BB * TPB, 256, 0, stream>>>(valA, s_in, qbuf, kbuf, valB, dst);
        state_kernel<<<BB, 1024, 0, stream>>>(s_in, dst, (l == 2) ? out : s_out);
        ffn_kernel<<<(MM + PT - 1) / PT, 256, 0, stream>>>(
            valB, W1 + (size_t)l * DD * DFF, b1 + (size_t)l * DFF,
            W2 + (size_t)l * DFF * DD, b2 + (size_t)l * DD,
            (l == 2) ? (out + MM) : valA);
        float* tmp = s_in; s_in = s_out; s_out = tmp;
    }
}

// Round 4
// 500.632 us; speedup vs baseline: 1.2891x; 1.2891x over previous
//
#include <hip/hip_runtime.h>
#include <hip/hip_bf16.h>
#include <math.h>

#define BB 2
#define SS 2048
#define NN 2049
#define MM (BB*NN)      // 4098 rows
#define DD 256
#define HR 128          // HEADS*RANK
#define NHEAD 4
#define WINW 64
#define KW 129          // 2*WIN+1
#define DFF 512
#define EPSF 1e-6f
#define TT 8            // attn token tile
#define TPB 257         // attn tiles per batch = ceil(NN/8)
#define PT 16           // proj token tile

typedef __attribute__((ext_vector_type(8))) short bf16x8;
typedef __attribute__((ext_vector_type(4))) float f32x4;

// ---------- reduction helpers (wave=64) ----------
__device__ __forceinline__ float wave_sum(float v) {
    v += __shfl_down(v, 32, 64);
    v += __shfl_down(v, 16, 64);
    v += __shfl_down(v, 8, 64);
    v += __shfl_down(v, 4, 64);
    v += __shfl_down(v, 2, 64);
    v += __shfl_down(v, 1, 64);
    return v;
}
__device__ __forceinline__ float wave_max(float v) {
    v = fmaxf(v, __shfl_down(v, 32, 64));
    v = fmaxf(v, __shfl_down(v, 16, 64));
    v = fmaxf(v, __shfl_down(v, 8, 64));
    v = fmaxf(v, __shfl_down(v, 4, 64));
    v = fmaxf(v, __shfl_down(v, 2, 64));
    v = fmaxf(v, __shfl_down(v, 1, 64));
    return v;
}
__device__ __forceinline__ float block_sum(float v, float* red) {
    v = wave_sum(v);
    __syncthreads();
    if ((threadIdx.x & 63) == 0) red[threadIdx.x >> 6] = v;
    __syncthreads();
    return red[0] + red[1] + red[2] + red[3];
}
__device__ __forceinline__ float sgnf(float x) {
    return (x > 0.f) ? 1.f : ((x < 0.f) ? -1.f : 0.f);
}
__device__ __forceinline__ ushort f2b(float x) {
    __hip_bfloat16 h = __float2bfloat16(x);
    return *(ushort*)&h;
}
__device__ __forceinline__ float b2f(ushort u) {
    unsigned int v = ((unsigned int)u) << 16;
    return *(float*)&v;
}

// ---------- weight pack: fp32 (K,N) row-major -> bf16 hi/lo MFMA-B fragments ----------
// chunk c = kt*(N/16)+nt, dst[(c*64+l)*8+j] = src[(kt*32+(l>>4)*8+j)*N + nt*16+(l&15)]
__global__ void pack2_kernel(const float* __restrict__ src,
                             ushort* __restrict__ dh, ushort* __restrict__ dl,
                             int K, int N) {
    int idx = blockIdx.x * 256 + threadIdx.x;
    if (idx >= K * N) return;
    int j = idx & 7;
    int l = (idx >> 3) & 63;
    int c = idx >> 9;
    int ntiles = N >> 4;
    int kt = c / ntiles, nt = c - kt * ntiles;
    int k = kt * 32 + ((l >> 4) << 3) + j;
    int n = nt * 16 + (l & 15);
    float s = src[(size_t)k * N + n];
    ushort h = f2b(s);
    dh[idx] = h;
    dl[idx] = f2b(s - b2f(h));
}

// ---------- embed ----------
__global__ void embed_kernel(const int* __restrict__ ids,
                             const float* __restrict__ emb,
                             const float* __restrict__ pos,
                             const float* __restrict__ anchor_val,
                             const float* __restrict__ anchor_state,
                             const float* __restrict__ Ws,
                             const float* __restrict__ bs,
                             float* __restrict__ val,
                             float* __restrict__ state) {
    __shared__ float red[4];
    int row = blockIdx.x;
    int t = threadIdx.x;
    int b = row / NN, n = row % NN;
    float e;
    if (n == 0) {
        e = anchor_val[t];
    } else {
        int id = ids[b * SS + (n - 1)];
        e = emb[(size_t)id * DD + t] + pos[(size_t)(n - 1) * DD + t];
    }
    float ss = block_sum(e * e, red);
    float ts = block_sum(e * Ws[t], red);
    float rn = 1.f / fmaxf(sqrtf(ss), EPSF);
    val[(size_t)row * DD + t] = e * rn;
    if (t == 0) state[row] = (n == 0) ? anchor_state[0] : (ts + bs[0]);
}

// ---------- q/k projection (fp32, 16-token tile) ----------
__global__ void proj_kernel(const float* __restrict__ val,
                            const float* __restrict__ U,
                            const float* __restrict__ V,
                            float* __restrict__ q,
                            float* __restrict__ k) {
    __shared__ float vT[DD][20];
    int m0 = blockIdx.x * PT;
    int t = threadIdx.x;
    #pragma unroll
    for (int m = 0; m < PT; m++) {
        int row = m0 + m;
        vT[t][m] = (row < MM) ? val[(size_t)row * DD + t] : 0.f;
    }
    __syncthreads();
    const float* Wm = (t < HR) ? U : V;
    int o = t & 127;
    float acc[PT];
    #pragma unroll
    for (int m = 0; m < PT; m++) acc[m] = 0.f;
    for (int d = 0; d < DD; d++) {
        float w = Wm[(size_t)d * HR + o];
        float4 vv[4];
        vv[0] = *(const float4*)&vT[d][0];
        vv[1] = *(const float4*)&vT[d][4];
        vv[2] = *(const float4*)&vT[d][8];
        vv[3] = *(const float4*)&vT[d][12];
        #pragma unroll
        for (int g = 0; g < 4; g++) {
            acc[g*4+0] += vv[g].x * w;
            acc[g*4+1] += vv[g].y * w;
            acc[g*4+2] += vv[g].z * w;
            acc[g*4+3] += vv[g].w * w;
        }
    }
    float* outp = (t < HR) ? q : k;
    #pragma unroll
    for (int m = 0; m < PT; m++) {
        int row = m0 + m;
        if (row < MM) outp[(size_t)row * HR + o] = acc[m];
    }
}

// ---------- windowed signed-softmax attention, 8-token tile (fp32) ----------
__global__ void attn_kernel(const float* __restrict__ val_in,
                            const float* __restrict__ state_in,
                            const float* __restrict__ q,
                            const float* __restrict__ k,
                            float* __restrict__ val_out,
                            ushort* __restrict__ valb_hi,
                            ushort* __restrict__ valb_lo,
                            float* __restrict__ dstate_out) {
    __shared__ float qs[TT][HR];
    __shared__ float sc[TT][KW + 3];
    __shared__ float wgt2[144][TT];
    __shared__ float redS[TT][4];
    __shared__ float redM[TT][4];
    int b = blockIdx.x / TPB;
    int n0 = (blockIdx.x % TPB) * TT;
    int nt = NN - n0; if (nt > TT) nt = TT;
    int t = threadIdx.x;

    for (int i = t; i < nt * HR; i += 256)
        qs[i >> 7][i & 127] = q[((size_t)(b * NN + n0)) * HR + i];
    for (int i = t; i < 144 * TT; i += 256) ((float*)wgt2)[i] = 0.f;
    __syncthreads();

    for (int idx = t; idx < nt * KW; idx += 256) {
        int m = idx / KW;
        int tap = idx - m * KW;
        int j = n0 + m - WINW + tap;
        float sv = 0.f;
        if (j >= 0 && j < NN) {
            const float4* kr = (const float4*)&k[((size_t)(b * NN + j)) * HR];
            const float4* qr = (const float4*)&qs[m][0];
            float smax = -INFINITY;
            #pragma unroll
            for (int h = 0; h < NHEAD; h++) {
                float acc = 0.f;
                #pragma unroll
                for (int i4 = 0; i4 < 8; i4++) {
                    float4 kv = kr[h * 8 + i4];
                    float4 qv = qr[h * 8 + i4];
                    acc += kv.x*qv.x + kv.y*qv.y + kv.z*qv.z + kv.w*qv.w;
                }
                smax = fmaxf(smax, acc);
            }
            sv = smax * 0.17677669529663687f;
        }
        sc[m][tap] = sv;
    }
    __syncthreads();

    {
        int g = t >> 5, l = t & 31;
        if (g < nt) {
            int n = n0 + g;
            int lo = (n - WINW < 0) ? (WINW - n) : 0;
            int hi = (n + WINW > NN - 1) ? (KW - 1 - (n + WINW - (NN - 1))) : (KW - 1);
            float mx = -INFINITY;
            for (int tap = lo + l; tap <= hi; tap += 32)
                mx = fmaxf(mx, fabsf(sc[g][tap]));
            for (int off = 16; off > 0; off >>= 1)
                mx = fmaxf(mx, __shfl_xor(mx, off, 64));
            float sum = 0.f;
            for (int tap = lo + l; tap <= hi; tap += 32)
                sum += expf(fabsf(sc[g][tap]) - mx);
            for (int off = 16; off > 0; off >>= 1)
                sum += __shfl_xor(sum, off, 64);
            float inv = 1.f / sum;
            float ds = 0.f;
            for (int tap = lo + l; tap <= hi; tap += 32) {
                float s = sc[g][tap];
                float w = sgnf(s) * expf(fabsf(s) - mx) * inv;
                wgt2[tap + g][g] = w;
                ds += w * state_in[b * NN + (n - WINW + tap)];
            }
            for (int off = 16; off > 0; off >>= 1)
                ds += __shfl_xor(ds, off, 64);
            if (l == 0) dstate_out[b * NN + n] = ds;
        }
    }
    __syncthreads();

    int base = n0 - WINW;
    int jlo = (base < 0) ? -base : 0;
    int jmax = nt - 1 + 2 * WINW;
    int jhi = (base + jmax > NN - 1) ? (NN - 1 - base) : jmax;
    const float* vb = val_in + ((size_t)(b * NN + base)) * DD + t;
    float acc[TT] = {0.f,0.f,0.f,0.f,0.f,0.f,0.f,0.f};
    #pragma unroll 2
    for (int jj = jlo; jj <= jhi; jj++) {
        float v = vb[(size_t)jj * DD];
        float4 w0 = *(const float4*)&wgt2[jj][0];
        float4 w1 = *(const float4*)&wgt2[jj][4];
        acc[0] += v * w0.x; acc[1] += v * w0.y; acc[2] += v * w0.z; acc[3] += v * w0.w;
        acc[4] += v * w1.x; acc[5] += v * w1.y; acc[6] += v * w1.z; acc[7] += v * w1.w;
    }

    int wid = t >> 6;
    float upd[TT];
    #pragma unroll
    for (int m = 0; m < TT; m++) {
        float vold = 0.f;
        if (m < nt) vold = val_in[((size_t)(b * NN + n0 + m)) * DD + t];
        float u = vold + acc[m];
        upd[m] = u;
        float s = wave_sum(u * u);
        float mx = wave_max(fabsf(acc[m]));
        if ((t & 63) == 0) { redS[m][wid] = s; redM[m][wid] = mx; }
    }
    __syncthreads();
    for (int m = 0; m < nt; m++) {
        float ss = redS[m][0] + redS[m][1] + redS[m][2] + redS[m][3];
        float mab = fmaxf(fmaxf(redM[m][0], redM[m][1]), fmaxf(redM[m][2], redM[m][3]));
        float rn = 1.f / fmaxf(sqrtf(ss), EPSF);
        float u = upd[m];
        float o = (mab > 0.f) ? u * rn : u;
        size_t oi = ((size_t)(b * NN + n0 + m)) * DD + t;
        val_out[oi] = o;
        ushort h = f2b(o);
        valb_hi[oi] = h;
        valb_lo[oi] = f2b(o - b2f(h));
    }
}

// ---------- state update ----------
__global__ void state_kernel(const float* __restrict__ state_in,
                             const float* __restrict__ dstate,
                             float* __restrict__ state_out) {
    __shared__ float xs[NN];
    __shared__ float redA[16];
    __shared__ float redB[16];
    int b = blockIdx.x, t = threadIdx.x;
    float lmax = -INFINITY;
    for (int n = t; n < NN; n += 1024) {
        float x = state_in[b * NN + n] + dstate[b * NN + n];
        xs[n] = x;
        lmax = fmaxf(lmax, fabsf(x));
    }
    lmax = wave_max(lmax);
    if ((t & 63) == 0) redA[t >> 6] = lmax;
    __syncthreads();
    float m = redA[0];
    #pragma unroll
    for (int i = 1; i < 16; i++) m = fmaxf(m, redA[i]);
    float lsum = 0.f;
    for (int n = t; n < NN; n += 1024) lsum += expf(fabsf(xs[n]) - m);
    lsum = wave_sum(lsum);
    if ((t & 63) == 0) redB[t >> 6] = lsum;
    __syncthreads();
    float ssum = 0.f;
    #pragma unroll
    for (int i = 0; i < 16; i++) ssum += redB[i];
    float inv = 1.f / ssum;
    for (int n = t; n < NN; n += 1024) {
        float x = xs[n];
        state_out[b * NN + n] = sgnf(x) * expf(fabsf(x) - m) * inv;
    }
}

// ---------- FFN: bf16x3 compensated MFMA, 16 tokens/block, 4 waves n-split ----------
__global__ void ffn_kernel(const ushort* __restrict__ XbH,  // bf16-hi val [MM][256]
                           const ushort* __restrict__ XbL,  // bf16-lo val
                           const float*  __restrict__ Xf,   // fp32 val
                           const ushort* __restrict__ W1h, const ushort* __restrict__ W1l,
                           const float*  __restrict__ b1,
                           const ushort* __restrict__ W2h, const ushort* __restrict__ W2l,
                           const float*  __restrict__ b2,
                           float* __restrict__ val_out) {
    __shared__ ushort HtH[16 * 520];   // 16.6 KB
    __shared__ ushort HtL[16 * 520];   // 16.6 KB
    __shared__ float red[16][17];
    __shared__ float rrn[16];
    float* Yt = (float*)HtH;           // reuse after GEMM2 (16*257*4 <= 16*520*2)

    int t = threadIdx.x;
    int w = t >> 6, l = t & 63;
    int m0 = blockIdx.x * 16;
    int lm = l & 15;              // lane's m
    int lk = (l >> 4) << 3;       // lane's k offset
    int cm = (l >> 4) << 2;       // C-frag row base

    // ---- GEMM1: X(16x256) @ W1(256x512); wave w -> n in [128w,128w+128)
    f32x4 acc[8];
    #pragma unroll
    for (int i = 0; i < 8; i++) acc[i] = (f32x4)(0.f);
    const ushort* ah_base = XbH + (size_t)(m0 + lm) * DD + lk;
    const ushort* al_base = XbL + (size_t)(m0 + lm) * DD + lk;
    bool arow_ok = (m0 + lm) < MM;
    for (int kt = 0; kt < 8; kt++) {
        bf16x8 afh = (bf16x8){0,0,0,0,0,0,0,0};
        bf16x8 afl = (bf16x8){0,0,0,0,0,0,0,0};
        if (arow_ok) {
            afh = *(const bf16x8*)(ah_base + kt * 32);
            afl = *(const bf16x8*)(al_base + kt * 32);
        }
        size_t cb = (((size_t)kt * 32 + w * 8) * 64 + l) * 8;
        #pragma unroll
        for (int n = 0; n < 8; n++) {
            bf16x8 bfh = *(const bf16x8*)(W1h + cb + (size_t)n * 64 * 8);
            bf16x8 bfl = *(const bf16x8*)(W1l + cb + (size_t)n * 64 * 8);
            acc[n] = __builtin_amdgcn_mfma_f32_16x16x32_bf16(afh, bfh, acc[n], 0, 0, 0);
            acc[n] = __builtin_amdgcn_mfma_f32_16x16x32_bf16(afl, bfh, acc[n], 0, 0, 0);
            acc[n] = __builtin_amdgcn_mfma_f32_16x16x32_bf16(afh, bfl, acc[n], 0, 0, 0);
        }
    }
    // bias + gelu -> Ht hi/lo bf16
    #pragma unroll
    for (int n = 0; n < 8; n++) {
        int gn = w * 128 + n * 16 + lm;
        float bb = b1[gn];
        #pragma unroll
        for (int r = 0; r < 4; r++) {
            float x = acc[n][r] + bb;
            float g = 0.5f * x * (1.f + erff(x * 0.70710678118654752f));
            ushort gh = f2b(g);
            HtH[(cm + r) * 520 + gn] = gh;
            HtL[(cm + r) * 520 + gn] = f2b(g - b2f(gh));
        }
    }
    __syncthreads();

    // ---- GEMM2: H(16x512) @ W2(512x256); wave w -> n in [64w,64w+64)
    f32x4 acc2[4];
    #pragma unroll
    for (int i = 0; i < 4; i++) acc2[i] = (f32x4)(0.f);
    for (int kt = 0; kt < 16; kt++) {
        bf16x8 afh = *(const bf16x8*)(HtH + lm * 520 + kt * 32 + lk);
        bf16x8 afl = *(const bf16x8*)(HtL + lm * 520 + kt * 32 + lk);
        size_t cb = (((size_t)kt * 16 + w * 4) * 64 + l) * 8;
        #pragma unroll
        for (int n = 0; n < 4; n++) {
            bf16x8 bfh = *(const bf16x8*)(W2h + cb + (size_t)n * 64 * 8);
            bf16x8 bfl = *(const bf16x8*)(W2l + cb + (size_t)n * 64 * 8);
            acc2[n] = __builtin_amdgcn_mfma_f32_16x16x32_bf16(afh, bfh, acc2[n], 0, 0, 0);
            acc2[n] = __builtin_amdgcn_mfma_f32_16x16x32_bf16(afl, bfh, acc2[n], 0, 0, 0);
            acc2[n] = __builtin_amdgcn_mfma_f32_16x16x32_bf16(afh, bfl, acc2[n], 0, 0, 0);
        }
    }
    __syncthreads();   // done with Ht; reuse as Yt

    // ---- epilogue: Y = X + C + b2
    #pragma unroll
    for (int n = 0; n < 4; n++) {
        int gn = w * 64 + n * 16 + lm;
        float bb = b2[gn];
        #pragma unroll
        for (int r = 0; r < 4; r++) {
            int row = m0 + cm + r;
            float xv = (row < MM) ? Xf[(size_t)row * DD + gn] : 0.f;
            Yt[(cm + r) * 257 + gn] = xv + acc2[n][r] + bb;
        }
    }
    __syncthreads();
    {
        int m = t & 15, p = t >> 4;
        float s = 0.f;
        #pragma unroll
        for (int i = 0; i < 16; i++) { float y = Yt[m * 257 + p * 16 + i]; s += y * y; }
        red[m][p] = s;
    }
    __syncthreads();
    if (t < 16) {
        float s = 0.f;
        #pragma unroll
        for (int i = 0; i < 16; i++) s += red[t][i];
        rrn[t] = 1.f / fmaxf(sqrtf(s), EPSF);
    }
    __syncthreads();
    #pragma unroll
    for (int m = 0; m < 16; m++) {
        int row = m0 + m;
        if (row < MM) val_out[(size_t)row * DD + t] = Yt[m * 257 + t] * rrn[m];
    }
}

extern "C" void kernel_launch(void* const* d_in, const int* in_sizes, int n_in,
                              void* d_out, int out_size, void* d_ws, size_t ws_size,
                              hipStream_t stream) {
    const int*   ids          = (const int*)d_in[0];
    const float* emb          = (const float*)d_in[1];
    const float* pos          = (const float*)d_in[2];
    const float* anchor_val   = (const float*)d_in[3];
    const float* anchor_state = (const float*)d_in[4];
    const float* Ws           = (const float*)d_in[5];
    const float* bs           = (const float*)d_in[6];
    const float* U            = (const float*)d_in[7];
    const float* V            = (const float*)d_in[8];
    const float* W1           = (const float*)d_in[9];
    const float* b1           = (const float*)d_in[10];
    const float* W2           = (const float*)d_in[11];
    const float* b2           = (const float*)d_in[12];
    float* out = (float*)d_out;

    // workspace layout (bf16 buffers first, 16B-aligned)
    ushort* valBbH = (ushort*)d_ws;                  // MM*DD
    ushort* valBbL = valBbH + (size_t)MM * DD;       // MM*DD
    ushort* W1ph   = valBbL + (size_t)MM * DD;       // 3*131072
    ushort* W1pl   = W1ph + 3 * 131072;
    ushort* W2ph   = W1pl + 3 * 131072;
    ushort* W2pl   = W2ph + 3 * 131072;
    float*  fbase  = (float*)(W2pl + 3 * 131072);
    float* valA = fbase;
    float* valB = valA + (size_t)MM * DD;
    float* qbuf = valB + (size_t)MM * DD;
    float* kbuf = qbuf + (size_t)MM * HR;
    float* st0  = kbuf + (size_t)MM * HR;
    float* st1  = st0 + MM;
    float* dst  = st1 + MM;

    for (int l = 0; l < 3; l++) {
        pack2_kernel<<<512, 256, 0, stream>>>(W1 + (size_t)l * DD * DFF,
                                              W1ph + (size_t)l * 131072,
                                              W1pl + (size_t)l * 131072, DD, DFF);
        pack2_kernel<<<512, 256, 0, stream>>>(W2 + (size_t)l * DFF * DD,
                                              W2ph + (size_t)l * 131072,
                                              W2pl + (size_t)l * 131072, DFF, DD);
    }

    embed_kernel<<<MM, 256, 0, stream>>>(ids, emb, pos, anchor_val, anchor_state,
                                         Ws, bs, valA, st0);
    float* s_in = st0;
    float* s_out = st1;
    for (int l = 0; l < 3; l++) {
        proj_kernel<<<(MM + PT - 1) / PT, 256, 0, stream>>>(
            valA, U + (size_t)l * DD * HR, V + (size_t)l * DD * HR, qbuf, kbuf);
        attn_kernel<<<BB * TPB, 256, 0, stream>>>(valA, s_in, qbuf, kbuf,
                                                  valB, valBbH, valBbL, dst);
        state_kernel<<<BB, 1024, 0, stream>>>(s_in, dst, (l == 2) ? out : s_out);
        ffn_kernel<<<(MM + 15) / 16, 256, 0, stream>>>(
            valBbH, valBbL, valB,
            W1ph + (size_t)l * 131072, W1pl + (size_t)l * 131072, b1 + (size_t)l * DFF,
            W2ph + (size_t)l * 131072, W2pl + (size_t)l * 131072, b2 + (size_t)l * DD,
            (l == 2) ? (out + MM) : valA);
        float* tmp = s_in; s_in = s_out; s_out = tmp;
    }
}

// Round 6
// 417.494 us; speedup vs baseline: 1.5458x; 1.1991x over previous
//
#include <hip/hip_runtime.h>
#include <hip/hip_bf16.h>
#include <math.h>

#define BB 2
#define SS 2048
#define NN 2049
#define MM (BB*NN)      // 4098 rows
#define DD 256
#define HR 128          // HEADS*RANK
#define NHEAD 4
#define WINW 64
#define DFF 512
#define EPSF 1e-6f
#define TB16 129        // ceil(NN/16) attn tiles per batch

typedef __attribute__((ext_vector_type(8))) short bf16x8;
typedef __attribute__((ext_vector_type(4))) float f32x4;

// ---------- helpers ----------
__device__ __forceinline__ float wave_sum(float v) {
    v += __shfl_down(v, 32, 64); v += __shfl_down(v, 16, 64);
    v += __shfl_down(v, 8, 64);  v += __shfl_down(v, 4, 64);
    v += __shfl_down(v, 2, 64);  v += __shfl_down(v, 1, 64);
    return v;
}
__device__ __forceinline__ float wave_max(float v) {
    v = fmaxf(v, __shfl_down(v, 32, 64)); v = fmaxf(v, __shfl_down(v, 16, 64));
    v = fmaxf(v, __shfl_down(v, 8, 64));  v = fmaxf(v, __shfl_down(v, 4, 64));
    v = fmaxf(v, __shfl_down(v, 2, 64));  v = fmaxf(v, __shfl_down(v, 1, 64));
    return v;
}
__device__ __forceinline__ float block_sum(float v, float* red) {
    v = wave_sum(v);
    __syncthreads();
    if ((threadIdx.x & 63) == 0) red[threadIdx.x >> 6] = v;
    __syncthreads();
    return red[0] + red[1] + red[2] + red[3];
}
__device__ __forceinline__ float sgnf(float x) {
    return (x > 0.f) ? 1.f : ((x < 0.f) ? -1.f : 0.f);
}
__device__ __forceinline__ ushort f2b(float x) {
    __hip_bfloat16 h = __float2bfloat16(x);
    return *(ushort*)&h;
}
__device__ __forceinline__ float b2f(ushort u) {
    unsigned int v = ((unsigned int)u) << 16;
    return *(float*)&v;
}
// 3-way split: x ~= b2f(h)+b2f(m)+b2f(l), 24 mantissa bits
__device__ __forceinline__ void split3(float x, ushort& h, ushort& m, ushort& l) {
    h = f2b(x);
    float r1 = x - b2f(h);
    m = f2b(r1);
    l = f2b(r1 - b2f(m));
}

// ---------- pack fp32 (K,N) row-major -> bf16 hi/lo MFMA-B fragments (2 planes) ----------
// chunk c = kt*(N/16)+nt; dst[(c*64+l)*8+j] = src[(kt*32+(l>>4)*8+j)*N + nt*16+(l&15)]
__global__ void pack2_kernel(const float* __restrict__ src,
                             ushort* __restrict__ dh, ushort* __restrict__ dl,
                             int K, int N) {
    int idx = blockIdx.x * 256 + threadIdx.x;
    if (idx >= K * N) return;
    int j = idx & 7;
    int l = (idx >> 3) & 63;
    int c = idx >> 9;
    int ntiles = N >> 4;
    int kt = c / ntiles, nt = c - kt * ntiles;
    int k = kt * 32 + ((l >> 4) << 3) + j;
    int n = nt * 16 + (l & 15);
    float s = src[(size_t)k * N + n];
    ushort h = f2b(s);
    dh[idx] = h;
    dl[idx] = f2b(s - b2f(h));
}

// ---------- pack 3 planes ----------
__global__ void pack3_kernel(const float* __restrict__ src,
                             ushort* __restrict__ d0, ushort* __restrict__ d1,
                             ushort* __restrict__ d2, int K, int N) {
    int idx = blockIdx.x * 256 + threadIdx.x;
    if (idx >= K * N) return;
    int j = idx & 7;
    int l = (idx >> 3) & 63;
    int c = idx >> 9;
    int ntiles = N >> 4;
    int kt = c / ntiles, nt = c - kt * ntiles;
    int k = kt * 32 + ((l >> 4) << 3) + j;
    int n = nt * 16 + (l & 15);
    ushort h, m, lo;
    split3(src[(size_t)k * N + n], h, m, lo);
    d0[idx] = h; d1[idx] = m; d2[idx] = lo;
}

// ---------- embed ----------
__global__ void embed_kernel(const int* __restrict__ ids,
                             const float* __restrict__ emb,
                             const float* __restrict__ pos,
                             const float* __restrict__ anchor_val,
                             const float* __restrict__ anchor_state,
                             const float* __restrict__ Ws,
                             const float* __restrict__ bs,
                             float* __restrict__ val,
                             ushort* __restrict__ v0, ushort* __restrict__ v1,
                             ushort* __restrict__ v2,
                             float* __restrict__ state) {
    __shared__ float red[4];
    int row = blockIdx.x;
    int t = threadIdx.x;
    int b = row / NN, n = row % NN;
    float e;
    if (n == 0) {
        e = anchor_val[t];
    } else {
        int id = ids[b * SS + (n - 1)];
        e = emb[(size_t)id * DD + t] + pos[(size_t)(n - 1) * DD + t];
    }
    float ss = block_sum(e * e, red);
    float ts = block_sum(e * Ws[t], red);
    float rn = 1.f / fmaxf(sqrtf(ss), EPSF);
    float o = e * rn;
    size_t oi = (size_t)row * DD + t;
    val[oi] = o;
    ushort h, m, lo;
    split3(o, h, m, lo);
    v0[oi] = h; v1[oi] = m; v2[oi] = lo;
    if (t == 0) state[row] = (n == 0) ? anchor_state[0] : (ts + bs[0]);
}

// ---------- q/k projection: 6-term bf16 MFMA (fp32-accurate), 16-token blocks ----------
__global__ void proj_kernel(const ushort* __restrict__ X0, const ushort* __restrict__ X1,
                            const ushort* __restrict__ X2,
                            const ushort* __restrict__ U0, const ushort* __restrict__ U1,
                            const ushort* __restrict__ U2,
                            const ushort* __restrict__ V0, const ushort* __restrict__ V1,
                            const ushort* __restrict__ V2,
                            ushort* __restrict__ q0, ushort* __restrict__ q1,
                            ushort* __restrict__ q2,
                            ushort* __restrict__ k0, ushort* __restrict__ k1,
                            ushort* __restrict__ k2) {
    int t = threadIdx.x;
    int w = t >> 6, l = t & 63;
    int lm = l & 15, quad = l >> 4;
    int m0 = blockIdx.x * 16;
    int arow = m0 + lm; if (arow > MM - 1) arow = MM - 1;
    const ushort* a0p = X0 + (size_t)arow * DD + quad * 8;
    const ushort* a1p = X1 + (size_t)arow * DD + quad * 8;
    const ushort* a2p = X2 + (size_t)arow * DD + quad * 8;
    bool isQ = (w < 2);
    const ushort* B0 = isQ ? U0 : V0;
    const ushort* B1 = isQ ? U1 : V1;
    const ushort* B2 = isQ ? U2 : V2;
    int ntb = (w & 1) * 4;
    f32x4 acc[4];
    #pragma unroll
    for (int j = 0; j < 4; j++) acc[j] = (f32x4)(0.f);
    for (int kt = 0; kt < 8; kt++) {
        bf16x8 a0 = *(const bf16x8*)(a0p + kt * 32);
        bf16x8 a1 = *(const bf16x8*)(a1p + kt * 32);
        bf16x8 a2 = *(const bf16x8*)(a2p + kt * 32);
        size_t cb = (((size_t)kt * 8 + ntb) * 64 + l) * 8;
        #pragma unroll
        for (int j = 0; j < 4; j++) {
            size_t o = cb + (size_t)j * 64 * 8;
            bf16x8 b0 = *(const bf16x8*)(B0 + o);
            bf16x8 b1 = *(const bf16x8*)(B1 + o);
            bf16x8 b2 = *(const bf16x8*)(B2 + o);
            acc[j] = __builtin_amdgcn_mfma_f32_16x16x32_bf16(a0, b0, acc[j], 0, 0, 0);
            acc[j] = __builtin_amdgcn_mfma_f32_16x16x32_bf16(a0, b1, acc[j], 0, 0, 0);
            acc[j] = __builtin_amdgcn_mfma_f32_16x16x32_bf16(a1, b0, acc[j], 0, 0, 0);
            acc[j] = __builtin_amdgcn_mfma_f32_16x16x32_bf16(a1, b1, acc[j], 0, 0, 0);
            acc[j] = __builtin_amdgcn_mfma_f32_16x16x32_bf16(a0, b2, acc[j], 0, 0, 0);
            acc[j] = __builtin_amdgcn_mfma_f32_16x16x32_bf16(a2, b0, acc[j], 0, 0, 0);
        }
    }
    ushort* o0 = isQ ? q0 : k0;
    ushort* o1 = isQ ? q1 : k1;
    ushort* o2 = isQ ? q2 : k2;
    #pragma unroll
    for (int j = 0; j < 4; j++) {
        int o = (ntb + j) * 16 + lm;
        #pragma unroll
        for (int r = 0; r < 4; r++) {
            int row = m0 + quad * 4 + r;
            if (row < MM) {
                ushort h, m, lo;
                split3(acc[j][r], h, m, lo);
                size_t oi = (size_t)row * HR + o;
                o0[oi] = h; o1[oi] = m; o2[oi] = lo;
            }
        }
    }
}

// ---------- attention: 6-term MFMA scores + fp32 softmax + VALU dval ----------
__global__ void attn_kernel(const float* __restrict__ val_in,
                            const float* __restrict__ state_in,
                            const ushort* __restrict__ q0, const ushort* __restrict__ q1,
                            const ushort* __restrict__ q2,
                            const ushort* __restrict__ k0, const ushort* __restrict__ k1,
                            const ushort* __restrict__ k2,
                            float* __restrict__ val_out,
                            ushort* __restrict__ vbH, ushort* __restrict__ vbM,
                            float* __restrict__ dstate_out) {
    __shared__ float sc4[NHEAD][16][148];          // 37.9 KB
    __shared__ __align__(16) float wgt2[144][20];  // 11.5 KB
    __shared__ float redS[16][4];
    __shared__ float redM[16][4];

    int b = blockIdx.x / TB16;
    int n0 = (blockIdx.x % TB16) * 16;
    int t = threadIdx.x;
    int w = t >> 6, l = t & 63;
    int lm = l & 15, quad = l >> 4;

    // ---- Phase A: scores per head (wave w = head w)
    {
        int qrow = n0 + lm; if (qrow > NN - 1) qrow = NN - 1;
        size_t qa = ((size_t)(b * NN + qrow)) * HR + w * 32 + quad * 8;
        bf16x8 a0 = *(const bf16x8*)(q0 + qa);
        bf16x8 a1 = *(const bf16x8*)(q1 + qa);
        bf16x8 a2 = *(const bf16x8*)(q2 + qa);
        #pragma unroll
        for (int jt = 0; jt < 9; jt++) {
            int j = n0 - 64 + jt * 16 + lm;
            j = (j < 0) ? 0 : ((j > NN - 1) ? NN - 1 : j);
            size_t ka = ((size_t)(b * NN + j)) * HR + w * 32 + quad * 8;
            bf16x8 b0 = *(const bf16x8*)(k0 + ka);
            bf16x8 b1 = *(const bf16x8*)(k1 + ka);
            bf16x8 b2 = *(const bf16x8*)(k2 + ka);
            f32x4 acc = (f32x4)(0.f);
            acc = __builtin_amdgcn_mfma_f32_16x16x32_bf16(a0, b0, acc, 0, 0, 0);
            acc = __builtin_amdgcn_mfma_f32_16x16x32_bf16(a0, b1, acc, 0, 0, 0);
            acc = __builtin_amdgcn_mfma_f32_16x16x32_bf16(a1, b0, acc, 0, 0, 0);
            acc = __builtin_amdgcn_mfma_f32_16x16x32_bf16(a1, b1, acc, 0, 0, 0);
            acc = __builtin_amdgcn_mfma_f32_16x16x32_bf16(a0, b2, acc, 0, 0, 0);
            acc = __builtin_amdgcn_mfma_f32_16x16x32_bf16(a2, b0, acc, 0, 0, 0);
            #pragma unroll
            for (int r = 0; r < 4; r++)
                sc4[w][quad * 4 + r][jt * 16 + lm] = acc[r];
        }
    }
    __syncthreads();

    // ---- Phase B: signed softmax per token (16 threads per token)
    {
        int m = t >> 4, p = t & 15;
        int n = n0 + m;
        bool tokv = (n < NN);
        float sv[9]; bool vv[9];
        float mx = -INFINITY;
        #pragma unroll
        for (int i = 0; i < 9; i++) {
            int tap = p + 16 * i;
            int j = n0 - 64 + tap;
            float s0 = sc4[0][m][tap], s1 = sc4[1][m][tap];
            float s2 = sc4[2][m][tap], s3 = sc4[3][m][tap];
            float s = fmaxf(fmaxf(s0, s1), fmaxf(s2, s3)) * 0.17677669529663687f;
            bool v = tokv && (tap >= m) && (tap <= m + 128) && (j >= 0) && (j < NN);
            sv[i] = s; vv[i] = v;
            if (v) mx = fmaxf(mx, fabsf(s));
        }
        for (int off = 8; off > 0; off >>= 1) mx = fmaxf(mx, __shfl_xor(mx, off, 64));
        float ee[9];
        float sum = 0.f;
        #pragma unroll
        for (int i = 0; i < 9; i++) {
            ee[i] = vv[i] ? expf(fabsf(sv[i]) - mx) : 0.f;
            sum += ee[i];
        }
        for (int off = 8; off > 0; off >>= 1) sum += __shfl_xor(sum, off, 64);
        float inv = (sum > 0.f) ? 1.f / sum : 0.f;
        float ds = 0.f;
        #pragma unroll
        for (int i = 0; i < 9; i++) {
            int tap = p + 16 * i;
            float wg = vv[i] ? sgnf(sv[i]) * ee[i] * inv : 0.f;
            wgt2[tap][m] = wg;
            if (vv[i]) ds += wg * state_in[b * NN + (n0 - 64 + tap)];
        }
        for (int off = 8; off > 0; off >>= 1) ds += __shfl_xor(ds, off, 64);
        if (p == 0 && tokv) dstate_out[b * NN + n] = ds;
    }
    __syncthreads();

    // ---- Phase C: dval = wgt @ V; thread = (4 tokens tg) x (4 d)
    {
        int d = (t >> 2) * 4;
        int tg = t & 3;
        int jlo = (n0 >= 64) ? 0 : (64 - n0);
        int jhi = NN - 1 - n0 + 64; if (jhi > 143) jhi = 143;
        const float* vbase = val_in + ((size_t)(b * NN + n0 - 64)) * DD + d;
        f32x4 acc[4];
        #pragma unroll
        for (int ti = 0; ti < 4; ti++) acc[ti] = (f32x4)(0.f);
        #pragma unroll 2
        for (int jj = jlo; jj <= jhi; jj++) {
            f32x4 v = *(const f32x4*)(vbase + (size_t)jj * DD);
            f32x4 wv = *(const f32x4*)&wgt2[jj][tg * 4];
            #pragma unroll
            for (int ti = 0; ti < 4; ti++) {
                float ws = wv[ti];
                acc[ti][0] += v[0] * ws; acc[ti][1] += v[1] * ws;
                acc[ti][2] += v[2] * ws; acc[ti][3] += v[3] * ws;
            }
        }
        f32x4 u[4];
        #pragma unroll
        for (int ti = 0; ti < 4; ti++) {
            int n = n0 + tg * 4 + ti;
            f32x4 vold = (f32x4)(0.f);
            if (n < NN) vold = *(const f32x4*)(val_in + ((size_t)(b * NN + n)) * DD + d);
            u[ti] = vold + acc[ti];
            float s = u[ti][0]*u[ti][0] + u[ti][1]*u[ti][1] + u[ti][2]*u[ti][2] + u[ti][3]*u[ti][3];
            float mb = fmaxf(fmaxf(fabsf(acc[ti][0]), fabsf(acc[ti][1])),
                             fmaxf(fabsf(acc[ti][2]), fabsf(acc[ti][3])));
            for (int off = 4; off <= 32; off <<= 1) {
                s += __shfl_xor(s, off, 64);
                mb = fmaxf(mb, __shfl_xor(mb, off, 64));
            }
            if ((l >> 2) == 0) { redS[tg * 4 + ti][w] = s; redM[tg * 4 + ti][w] = mb; }
        }
        __syncthreads();
        #pragma unroll
        for (int ti = 0; ti < 4; ti++) {
            int tok = tg * 4 + ti;
            int n = n0 + tok;
            if (n < NN) {
                float ss = redS[tok][0] + redS[tok][1] + redS[tok][2] + redS[tok][3];
                float mab = fmaxf(fmaxf(redM[tok][0], redM[tok][1]),
                                  fmaxf(redM[tok][2], redM[tok][3]));
                float rn = 1.f / fmaxf(sqrtf(ss), EPSF);
                f32x4 o = u[ti];
                if (mab > 0.f) { o[0] *= rn; o[1] *= rn; o[2] *= rn; o[3] *= rn; }
                size_t oi = ((size_t)(b * NN + n)) * DD + d;
                *(f32x4*)(val_out + oi) = o;
                ushort4 hv, mv;
                {
                    ushort h0 = f2b(o[0]); hv.x = h0; mv.x = f2b(o[0] - b2f(h0));
                    ushort h1 = f2b(o[1]); hv.y = h1; mv.y = f2b(o[1] - b2f(h1));
                    ushort h2 = f2b(o[2]); hv.z = h2; mv.z = f2b(o[2] - b2f(h2));
                    ushort h3 = f2b(o[3]); hv.w = h3; mv.w = f2b(o[3] - b2f(h3));
                }
                *(ushort4*)(vbH + oi) = hv;
                *(ushort4*)(vbM + oi) = mv;
            }
        }
    }
}

// ---------- state update ----------
__global__ void state_kernel(const float* __restrict__ state_in,
                             const float* __restrict__ dstate,
                             float* __restrict__ state_out) {
    __shared__ float xs[NN];
    __shared__ float redA[16];
    __shared__ float redB[16];
    int b = blockIdx.x, t = threadIdx.x;
    float lmax = -INFINITY;
    for (int n = t; n < NN; n += 1024) {
        float x = state_in[b * NN + n] + dstate[b * NN + n];
        xs[n] = x;
        lmax = fmaxf(lmax, fabsf(x));
    }
    lmax = wave_max(lmax);
    if ((t & 63) == 0) redA[t >> 6] = lmax;
    __syncthreads();
    float m = redA[0];
    #pragma unroll
    for (int i = 1; i < 16; i++) m = fmaxf(m, redA[i]);
    float lsum = 0.f;
    for (int n = t; n < NN; n += 1024) lsum += expf(fabsf(xs[n]) - m);
    lsum = wave_sum(lsum);
    if ((t & 63) == 0) redB[t >> 6] = lsum;
    __syncthreads();
    float ssum = 0.f;
    #pragma unroll
    for (int i = 0; i < 16; i++) ssum += redB[i];
    float inv = 1.f / ssum;
    for (int n = t; n < NN; n += 1024) {
        float x = xs[n];
        state_out[b * NN + n] = sgnf(x) * expf(fabsf(x) - m) * inv;
    }
}

// ---------- FFN: bf16x3 MFMA, 16 tokens/block ----------
__global__ void ffn_kernel(const ushort* __restrict__ XbH, const ushort* __restrict__ XbM,
                           const float*  __restrict__ Xf,
                           const ushort* __restrict__ W1h, const ushort* __restrict__ W1l,
                           const float*  __restrict__ b1,
                           const ushort* __restrict__ W2h, const ushort* __restrict__ W2l,
                           const float*  __restrict__ b2,
                           float* __restrict__ val_out,
                           ushort* __restrict__ o0, ushort* __restrict__ o1,
                           ushort* __restrict__ o2) {
    __shared__ ushort HtH[16 * 520];
    __shared__ ushort HtL[16 * 520];
    __shared__ float red[16][17];
    __shared__ float rrn[16];
    float* Yt = (float*)HtH;

    int t = threadIdx.x;
    int w = t >> 6, l = t & 63;
    int m0 = blockIdx.x * 16;
    int lm = l & 15;
    int lk = (l >> 4) << 3;
    int cm = (l >> 4) << 2;

    f32x4 acc[8];
    #pragma unroll
    for (int i = 0; i < 8; i++) acc[i] = (f32x4)(0.f);
    const ushort* ah_base = XbH + (size_t)(m0 + lm) * DD + lk;
    const ushort* al_base = XbM + (size_t)(m0 + lm) * DD + lk;
    bool arow_ok = (m0 + lm) < MM;
    for (int kt = 0; kt < 8; kt++) {
        bf16x8 afh = (bf16x8){0,0,0,0,0,0,0,0};
        bf16x8 afl = (bf16x8){0,0,0,0,0,0,0,0};
        if (arow_ok) {
            afh = *(const bf16x8*)(ah_base + kt * 32);
            afl = *(const bf16x8*)(al_base + kt * 32);
        }
        size_t cb = (((size_t)kt * 32 + w * 8) * 64 + l) * 8;
        #pragma unroll
        for (int n = 0; n < 8; n++) {
            bf16x8 bfh = *(const bf16x8*)(W1h + cb + (size_t)n * 64 * 8);
            bf16x8 bfl = *(const bf16x8*)(W1l + cb + (size_t)n * 64 * 8);
            acc[n] = __builtin_amdgcn_mfma_f32_16x16x32_bf16(afh, bfh, acc[n], 0, 0, 0);
            acc[n] = __builtin_amdgcn_mfma_f32_16x16x32_bf16(afl, bfh, acc[n], 0, 0, 0);
            acc[n] = __builtin_amdgcn_mfma_f32_16x16x32_bf16(afh, bfl, acc[n], 0, 0, 0);
        }
    }
    #pragma unroll
    for (int n = 0; n < 8; n++) {
        int gn = w * 128 + n * 16 + lm;
        float bb = b1[gn];
        #pragma unroll
        for (int r = 0; r < 4; r++) {
            float x = acc[n][r] + bb;
            float g = 0.5f * x * (1.f + erff(x * 0.70710678118654752f));
            ushort gh = f2b(g);
            HtH[(cm + r) * 520 + gn] = gh;
            HtL[(cm + r) * 520 + gn] = f2b(g - b2f(gh));
        }
    }
    __syncthreads();

    f32x4 acc2[4];
    #pragma unroll
    for (int i = 0; i < 4; i++) acc2[i] = (f32x4)(0.f);
    for (int kt = 0; kt < 16; kt++) {
        bf16x8 afh = *(const bf16x8*)(HtH + lm * 520 + kt * 32 + lk);
        bf16x8 afl = *(const bf16x8*)(HtL + lm * 520 + kt * 32 + lk);
        size_t cb = (((size_t)kt * 16 + w * 4) * 64 + l) * 8;
        #pragma unroll
        for (int n = 0; n < 4; n++) {
            bf16x8 bfh = *(const bf16x8*)(W2h + cb + (size_t)n * 64 * 8);
            bf16x8 bfl = *(const bf16x8*)(W2l + cb + (size_t)n * 64 * 8);
            acc2[n] = __builtin_amdgcn_mfma_f32_16x16x32_bf16(afh, bfh, acc2[n], 0, 0, 0);
            acc2[n] = __builtin_amdgcn_mfma_f32_16x16x32_bf16(afl, bfh, acc2[n], 0, 0, 0);
            acc2[n] = __builtin_amdgcn_mfma_f32_16x16x32_bf16(afh, bfl, acc2[n], 0, 0, 0);
        }
    }
    __syncthreads();

    #pragma unroll
    for (int n = 0; n < 4; n++) {
        int gn = w * 64 + n * 16 + lm;
        float bb = b2[gn];
        #pragma unroll
        for (int r = 0; r < 4; r++) {
            int row = m0 + cm + r;
            float xv = (row < MM) ? Xf[(size_t)row * DD + gn] : 0.f;
            Yt[(cm + r) * 257 + gn] = xv + acc2[n][r] + bb;
        }
    }
    __syncthreads();
    {
        int m = t & 15, p = t >> 4;
        float s = 0.f;
        #pragma unroll
        for (int i = 0; i < 16; i++) { float y = Yt[m * 257 + p * 16 + i]; s += y * y; }
        red[m][p] = s;
    }
    __syncthreads();
    if (t < 16) {
        float s = 0.f;
        #pragma unroll
        for (int i = 0; i < 16; i++) s += red[t][i];
        rrn[t] = 1.f / fmaxf(sqrtf(s), EPSF);
    }
    __syncthreads();
    #pragma unroll
    for (int m = 0; m < 16; m++) {
        int row = m0 + m;
        if (row < MM) {
            float o = Yt[m * 257 + t] * rrn[m];
            size_t oi = (size_t)row * DD + t;
            val_out[oi] = o;
            ushort h, mm, lo;
            split3(o, h, mm, lo);
            o0[oi] = h; o1[oi] = mm; o2[oi] = lo;
        }
    }
}

extern "C" void kernel_launch(void* const* d_in, const int* in_sizes, int n_in,
                              void* d_out, int out_size, void* d_ws, size_t ws_size,
                              hipStream_t stream) {
    const int*   ids          = (const int*)d_in[0];
    const float* emb          = (const float*)d_in[1];
    const float* pos          = (const float*)d_in[2];
    const float* anchor_val   = (const float*)d_in[3];
    const float* anchor_state = (const float*)d_in[4];
    const float* Ws           = (const float*)d_in[5];
    const float* bs           = (const float*)d_in[6];
    const float* U            = (const float*)d_in[7];
    const float* V            = (const float*)d_in[8];
    const float* W1           = (const float*)d_in[9];
    const float* b1           = (const float*)d_in[10];
    const float* W2           = (const float*)d_in[11];
    const float* b2           = (const float*)d_in[12];
    float* out = (float*)d_out;

    // ---- workspace (ushort planes first, 16B-aligned blocks) ----
    ushort* p = (ushort*)d_ws;
    ushort* vA0 = p; p += (size_t)MM * DD;
    ushort* vA1 = p; p += (size_t)MM * DD;
    ushort* vA2 = p; p += (size_t)MM * DD;
    ushort* vB0 = p; p += (size_t)MM * DD;
    ushort* vB1 = p; p += (size_t)MM * DD;
    ushort* q0b = p; p += (size_t)MM * HR;
    ushort* q1b = p; p += (size_t)MM * HR;
    ushort* q2b = p; p += (size_t)MM * HR;
    ushort* k0b = p; p += (size_t)MM * HR;
    ushort* k1b = p; p += (size_t)MM * HR;
    ushort* k2b = p; p += (size_t)MM * HR;
    ushort* W1ph = p; p += 3 * 131072;
    ushort* W1pl = p; p += 3 * 131072;
    ushort* W2ph = p; p += 3 * 131072;
    ushort* W2pl = p; p += 3 * 131072;
    ushort* U0p = p; p += 3 * 32768;
    ushort* U1p = p; p += 3 * 32768;
    ushort* U2p = p; p += 3 * 32768;
    ushort* V0p = p; p += 3 * 32768;
    ushort* V1p = p; p += 3 * 32768;
    ushort* V2p = p; p += 3 * 32768;
    float* f = (float*)p;
    float* valA = f; f += (size_t)MM * DD;
    float* valB = f; f += (size_t)MM * DD;
    float* st0  = f; f += MM;
    float* st1  = f; f += MM;
    float* dst  = f; f += MM;

    for (int l = 0; l < 3; l++) {
        pack2_kernel<<<512, 256, 0, stream>>>(W1 + (size_t)l * DD * DFF,
                                              W1ph + (size_t)l * 131072,
                                              W1pl + (size_t)l * 131072, DD, DFF);
        pack2_kernel<<<512, 256, 0, stream>>>(W2 + (size_t)l * DFF * DD,
                                              W2ph + (size_t)l * 131072,
                                              W2pl + (size_t)l * 131072, DFF, DD);
        pack3_kernel<<<128, 256, 0, stream>>>(U + (size_t)l * DD * HR,
                                              U0p + (size_t)l * 32768,
                                              U1p + (size_t)l * 32768,
                                              U2p + (size_t)l * 32768, DD, HR);
        pack3_kernel<<<128, 256, 0, stream>>>(V + (size_t)l * DD * HR,
                                              V0p + (size_t)l * 32768,
                                              V1p + (size_t)l * 32768,
                                              V2p + (size_t)l * 32768, DD, HR);
    }

    embed_kernel<<<MM, 256, 0, stream>>>(ids, emb, pos, anchor_val, anchor_state,
                                         Ws, bs, valA, vA0, vA1, vA2, st0);
    float* s_in = st0;
    float* s_out = st1;
    for (int l = 0; l < 3; l++) {
        proj_kernel<<<(MM + 15) / 16, 256, 0, stream>>>(
            vA0, vA1, vA2,
            U0p + (size_t)l * 32768, U1p + (size_t)l * 32768, U2p + (size_t)l * 32768,
            V0p + (size_t)l * 32768, V1p + (size_t)l * 32768, V2p + (size_t)l * 32768,
            q0b, q1b, q2b, k0b, k1b, k2b);
        attn_kernel<<<BB * TB16, 256, 0, stream>>>(valA, s_in,
                                                   q0b, q1b, q2b, k0b, k1b, k2b,
                                                   valB, vB0, vB1, dst);
        state_kernel<<<BB, 1024, 0, stream>>>(s_in, dst, (l == 2) ? out : s_out);
        ffn_kernel<<<(MM + 15) / 16, 256, 0, stream>>>(
            vB0, vB1, valB,
            W1ph + (size_t)l * 131072, W1pl + (size_t)l * 131072, b1 + (size_t)l * DFF,
            W2ph + (size_t)l * 131072, W2pl + (size_t)l * 131072, b2 + (size_t)l * DD,
            (l == 2) ? (out + MM) : valA, vA0, vA1, vA2);
        float* tmp = s_in; s_in = s_out; s_out = tmp;
    }
}